// Round 11
// baseline (351.960 us; speedup 1.0000x reference)
//
#include <hip/hip_runtime.h>
#include <hip/hip_bf16.h>

// PseudoTripletLoss on MI355X (gfx950) — ABLATION ROUND
// Real path: K1 -> tri_loss_t<0> (R6-best 544-block structure) -> K3.
// Ablation dispatches (results -> scratch, unused):
//   tri_loss_t<1>: full body x8        (baseline for the x8 family)
//   tri_loss_t<2>: no-stage x8         (B staged once; ds_read+MFMA+epilogue x8)
//   tri_loss_t<3>: stage-only x8       (global_load_lds+barriers; no compute)
//   tri_loss_t<4>: no-epilogue x8      (stage+ds_read+MFMA; trivial acc consume)
// Purpose: attribute the ~20 µs of unexplained stall to stage-chain vs
// compute vs epilogue vs serialization. Variants are sized >42 us so they
// appear in the top-5 dispatch table past the ~40 us fillBuffer rows.

typedef __attribute__((ext_vector_type(8))) short short8;
typedef __attribute__((ext_vector_type(4))) float f32x4;

#define DIM 128
#define MARGIN 0.1f
#define CHUNK 4      // 128-col tiles per block -> up to 8 subtiles of 64 cols

typedef const void __attribute__((address_space(1)))* gas_ptr;
typedef void __attribute__((address_space(3)))* las_ptr;

static __device__ __forceinline__ void load16_to_lds(const void* g, void* l) {
    __builtin_amdgcn_global_load_lds((gas_ptr)g, (las_ptr)l, 16, 0, 0);
}

static __device__ __forceinline__ unsigned short f2bf(float f) {
    unsigned int u = __builtin_bit_cast(unsigned int, f);
    u += 0x7FFFu + ((u >> 16) & 1u);   // round-to-nearest-even
    return (unsigned short)(u >> 16);
}

// Stage a 64x128 bf16 tile into a 16 KB LDS buf (coalesced global_load_lds,
// XOR involution on the SOURCE column; LDS dest lane-linear).
static __device__ __forceinline__ void stage64(const short* __restrict__ en, int row0,
                                               short* buf, int tid) {
    const char* src = (const char*)(en + (size_t)row0 * DIM);
    char* dst = (char*)buf;
    const int r_lo = tid >> 4;
    const int s    = tid & 15;
    #pragma unroll
    for (int p = 0; p < 4; ++p) {
        const int r  = p * 16 + r_lo;
        const int sc = (s ^ (r & 7)) << 4;
        load16_to_lds(src + (size_t)r * 256 + sc, dst + r * 256 + s * 16);
    }
}

static __device__ __forceinline__ short8 read_frag(const short* buf, int row, int slot) {
    const int ps = slot ^ (row & 7);
    return *(const short8*)(buf + row * DIM + ps * 8);
}

// ---------------- K1: normalize rows, write packed bf16 ----------------
__global__ void __launch_bounds__(256) norm_bf16_kernel(const float* __restrict__ e,
                                                        unsigned int* __restrict__ en_packed) {
    const int row  = blockIdx.x * 4 + (threadIdx.x >> 6);
    const int lane = threadIdx.x & 63;
    const float2 v = *reinterpret_cast<const float2*>(e + row * DIM + lane * 2);
    float s = v.x * v.x + v.y * v.y;
    #pragma unroll
    for (int off = 32; off; off >>= 1) s += __shfl_xor(s, off, 64);
    const float scale = 1.0f / fmaxf(sqrtf(s), 1e-8f);
    const unsigned int lo = f2bf(v.x * scale);
    const unsigned int hi = f2bf(v.y * scale);
    en_packed[row * (DIM / 2) + lane] = (hi << 16) | lo;
}

// ---------------- K2 template: R6 structure + ablation modes ----------------
// MODE 0: real, 1 rep, writes partials.  1: full x8.  2: no-stage x8.
// MODE 3: stage-only x8.                 4: no-epilogue x8.
template<int MODE>
__global__ void __launch_bounds__(256, 3)
tri_loss_t(const short* __restrict__ en, const int* __restrict__ labels,
           float* __restrict__ outp, int nt) {
    constexpr int  REPS    = (MODE == 0) ? 1 : 8;
    constexpr bool STAGE   = (MODE != 2);
    constexpr bool COMPUTE = (MODE != 3);
    constexpr bool EPI     = (MODE <= 2);

    __shared__ __align__(16) short buf[2][64 * DIM];   // 2 x 16 KB
    __shared__ float wsum[4];

    // exact (strip bi, chunk t) decode
    int t  = blockIdx.x;
    int bi = 0, cnt = (nt + CHUNK - 1) / CHUNK;
    #pragma unroll 1
    while (t >= cnt) { t -= cnt; ++bi; cnt = (nt - bi + CHUNK - 1) / CHUNK; }
    const int jbase = bi + t * CHUNK;
    const int nsub  = 2 * min(CHUNK, nt - jbase);

    const int tid  = threadIdx.x;
    const int lane = tid & 63;
    const int wid  = tid >> 6;          // 4 waves = 2x2 over (128 rows x 64 cols)
    const int wr   = wid >> 1, wc = wid & 1;
    const int lm   = lane & 15;
    const int hi   = lane >> 4;

    // prologue: stage A strip halves into the two buffers
    stage64(en, bi * 128,      &buf[0][0], tid);
    stage64(en, bi * 128 + 64, &buf[1][0], tid);

    const int r0w = bi * 128 + wr * 64;
    int4 li[4];
    #pragma unroll
    for (int m = 0; m < 4; ++m) li[m] = *(const int4*)(labels + r0w + m * 16 + hi * 4);

    __syncthreads();

    short8 a[4][4];
    const short* Abuf = &buf[wr][0];
    #pragma unroll
    for (int m = 0; m < 4; ++m)
        #pragma unroll
        for (int ks = 0; ks < 4; ++ks)
            a[m][ks] = read_frag(Abuf, m * 16 + lm, hi + ks * 4);

    __syncthreads();

    stage64(en, jbase * 128, &buf[0][0], tid);         // B subtile 0
    if (!STAGE)                                        // MODE 2: pre-stage both
        stage64(en, jbase * 128 + 64, &buf[1][0], tid);
    __syncthreads();

    float lsum = 0.0f;
    const int rb = hi * 4;

    if (!COMPUTE) {  // keep A-extract ds_reads alive in MODE 3 (cheap)
        #pragma unroll
        for (int m = 0; m < 4; ++m) lsum += (float)a[m][0][0];
    }

    #pragma unroll 1
    for (int rep = 0; rep < REPS; ++rep) {
        #pragma unroll 1
        for (int s = 0; s < nsub; ++s) {
            const short* cur = &buf[s & 1][0];

            if (STAGE) {
                if (MODE == 0) {
                    if (s + 1 < nsub)
                        stage64(en, jbase * 128 + (s + 1) * 64, &buf[(s + 1) & 1][0], tid);
                } else {   // looped variants: constant staging rate, wrap columns
                    const int snext = (s + 1) % nsub;
                    stage64(en, jbase * 128 + snext * 64, &buf[(s + 1) & 1][0], tid);
                }
            }

            if (COMPUTE) {
                const int c0 = jbase * 128 + s * 64 + wc * 32;
                f32x4 acc[4][2] = {};
                #pragma unroll
                for (int ks = 0; ks < 4; ++ks) {
                    short8 b[2];
                    b[0] = read_frag(cur, wc * 32 + lm,      hi + ks * 4);
                    b[1] = read_frag(cur, wc * 32 + 16 + lm, hi + ks * 4);
                    #pragma unroll
                    for (int m = 0; m < 4; ++m)
                        #pragma unroll
                        for (int n = 0; n < 2; ++n)
                            acc[m][n] = __builtin_amdgcn_mfma_f32_16x16x32_bf16(a[m][ks], b[n], acc[m][n], 0, 0, 0);
                }

                if (EPI) {
                    int labj[2];
                    labj[0] = labels[c0 + lm];
                    labj[1] = labels[c0 + 16 + lm];
                    const bool diag = (jbase == bi) && (s < 2);
                    #pragma unroll
                    for (int m = 0; m < 4; ++m) {
                        #pragma unroll
                        for (int r = 0; r < 4; ++r) {
                            const int i   = r0w + m * 16 + rb + r;
                            const int l_i = ((const int*)&li[m])[r];
                            #pragma unroll
                            for (int n = 0; n < 2; ++n) {
                                const int j  = c0 + n * 16 + lm;
                                const float sv = acc[m][n][r];
                                const float t2 = (l_i == labj[n]) ? (1.0f - sv) : (sv - MARGIN);
                                const float v  = fmaxf(t2, 0.0f);
                                if (!diag || i < j) lsum += v;
                            }
                        }
                    }
                } else {   // MODE 4: consume acc cheaply to keep MFMAs live
                    #pragma unroll
                    for (int m = 0; m < 4; ++m)
                        #pragma unroll
                        for (int n = 0; n < 2; ++n)
                            lsum += acc[m][n][0];
                }
            }
            __syncthreads();
        }
    }

    #pragma unroll
    for (int off = 32; off; off >>= 1) lsum += __shfl_down(lsum, off, 64);
    if (lane == 0) wsum[wid] = lsum;
    __syncthreads();
    if (tid == 0) outp[blockIdx.x] = wsum[0] + wsum[1] + wsum[2] + wsum[3];
}

// ---------------- K3: final deterministic reduce ----------------
__global__ void __launch_bounds__(256) final_reduce_kernel(const float* __restrict__ partials,
                                                           float* __restrict__ out,
                                                           int n, float inv_denom) {
    float s = 0.0f;
    for (int i = threadIdx.x; i < n; i += 256) s += partials[i];
    #pragma unroll
    for (int off = 32; off; off >>= 1) s += __shfl_xor(s, off, 64);
    __shared__ float wsum[4];
    if ((threadIdx.x & 63) == 0) wsum[threadIdx.x >> 6] = s;
    __syncthreads();
    if (threadIdx.x == 0) out[0] = (wsum[0] + wsum[1] + wsum[2] + wsum[3]) * inv_denom;
}

extern "C" void kernel_launch(void* const* d_in, const int* in_sizes, int n_in,
                              void* d_out, int out_size, void* d_ws, size_t ws_size,
                              hipStream_t stream) {
    const float* emb    = (const float*)d_in[0];
    const int*   labels = (const int*)d_in[1];
    float*       out    = (float*)d_out;

    const int n  = in_sizes[1];      // 8192
    const int nt = n / 128;          // 64 strips

    int Tc = 0;                      // 544 blocks at CHUNK=4
    for (int i = 0; i < nt; ++i) Tc += (nt - i + CHUNK - 1) / CHUNK;

    unsigned int* en_packed = (unsigned int*)d_ws;                 // 2 MB
    short*        en        = (short*)d_ws;
    float*        partials  = (float*)((char*)d_ws + (size_t)n * DIM * 2);
    float*        scratch   = partials + Tc;                        // ablation sink

    norm_bf16_kernel<<<n / 4, 256, 0, stream>>>(emb, en_packed);

    // real pipeline
    tri_loss_t<0><<<Tc, 256, 0, stream>>>(en, labels, partials, nt);
    const float inv_denom = (float)(1.0 / ((double)n * (double)(n - 1)));
    final_reduce_kernel<<<1, 256, 0, stream>>>(partials, out, Tc, inv_denom);

    // ablation dispatches (outputs unused; deterministic; scratch only)
    tri_loss_t<1><<<Tc, 256, 0, stream>>>(en, labels, scratch, nt);
    tri_loss_t<2><<<Tc, 256, 0, stream>>>(en, labels, scratch, nt);
    tri_loss_t<3><<<Tc, 256, 0, stream>>>(en, labels, scratch, nt);
    tri_loss_t<4><<<Tc, 256, 0, stream>>>(en, labels, scratch, nt);
}

// Round 12
// 32.902 us; speedup vs baseline: 10.6971x; 10.6971x over previous
//
#include <hip/hip_runtime.h>
#include <hip/hip_bf16.h>

// PseudoTripletLoss on MI355X (gfx950)
// loss = sum_{i<j} [ same(i,j) ? relu(1 - cos_ij) : relu(cos_ij - 0.1) ] / (n(n-1))
//
// R11 ablation: epilogue = ~85% of K2 (full==no-stage>>stage-only~no-epilogue).
// R12: (1) MFMA pipelined one subtile ahead of the epilogue (epilogue overlaps
//      next subtile's MFMA+stage), (2) slim branchless epilogue:
//      vsum += same ? (1-s) : relu(s-0.1)   [relu(1-s)=1-s exact: |s|<=~0.5 off-diag]
// Structure: R6-best 544 triangular (128-row strip, 512-col chunk) blocks,
// 64x128 B subtiles double-buffered via coalesced global_load_lds, XOR swizzle.

typedef __attribute__((ext_vector_type(8))) short short8;
typedef __attribute__((ext_vector_type(4))) float f32x4;

#define DIM 128
#define MARGIN 0.1f
#define CHUNK 4      // 128-col tiles per block -> up to 8 subtiles of 64 cols

typedef const void __attribute__((address_space(1)))* gas_ptr;
typedef void __attribute__((address_space(3)))* las_ptr;

static __device__ __forceinline__ void load16_to_lds(const void* g, void* l) {
    __builtin_amdgcn_global_load_lds((gas_ptr)g, (las_ptr)l, 16, 0, 0);
}

static __device__ __forceinline__ unsigned short f2bf(float f) {
    unsigned int u = __builtin_bit_cast(unsigned int, f);
    u += 0x7FFFu + ((u >> 16) & 1u);   // round-to-nearest-even
    return (unsigned short)(u >> 16);
}

// Stage a 64x128 bf16 tile into a 16 KB LDS buf (coalesced global_load_lds,
// XOR involution applied on the SOURCE column; LDS dest lane-linear).
static __device__ __forceinline__ void stage64(const short* __restrict__ en, int row0,
                                               short* buf, int tid) {
    const char* src = (const char*)(en + (size_t)row0 * DIM);
    char* dst = (char*)buf;
    const int r_lo = tid >> 4;
    const int s    = tid & 15;
    #pragma unroll
    for (int p = 0; p < 4; ++p) {
        const int r  = p * 16 + r_lo;
        const int sc = (s ^ (r & 7)) << 4;
        load16_to_lds(src + (size_t)r * 256 + sc, dst + r * 256 + s * 16);
    }
}

static __device__ __forceinline__ short8 read_frag(const short* buf, int row, int slot) {
    const int ps = slot ^ (row & 7);
    return *(const short8*)(buf + row * DIM + ps * 8);
}

// ---------------- K1: normalize rows, write packed bf16 ----------------
__global__ void __launch_bounds__(256) norm_bf16_kernel(const float* __restrict__ e,
                                                        unsigned int* __restrict__ en_packed) {
    const int row  = blockIdx.x * 4 + (threadIdx.x >> 6);
    const int lane = threadIdx.x & 63;
    const float2 v = *reinterpret_cast<const float2*>(e + row * DIM + lane * 2);
    float s = v.x * v.x + v.y * v.y;
    #pragma unroll
    for (int off = 32; off; off >>= 1) s += __shfl_xor(s, off, 64);
    const float scale = 1.0f / fmaxf(sqrtf(s), 1e-8f);
    const unsigned int lo = f2bf(v.x * scale);
    const unsigned int hi = f2bf(v.y * scale);
    en_packed[row * (DIM / 2) + lane] = (hi << 16) | lo;
}

// ---------------- K2: pipelined triangular subtile GEMM + slim epilogue ----------------

#define EPI_FAST(ACC, LJ)                                                          \
    _Pragma("unroll") for (int m = 0; m < 4; ++m)                                  \
        _Pragma("unroll") for (int n = 0; n < 2; ++n) {                            \
            const f32x4 sv   = ACC[m][n];                                          \
            const f32x4 base = sv - MARGIN;                                        \
            const f32x4 alt  = 1.0f - sv;                                          \
            _Pragma("unroll") for (int r = 0; r < 4; ++r) {                        \
                const float bv = fmaxf(base[r], 0.0f);                             \
                vsum[r] += (liv[m][r] == LJ[n]) ? alt[r] : bv;                     \
            }                                                                      \
        }

#define EPI_DIAG(ACC, LJ)                                                          \
    _Pragma("unroll") for (int m = 0; m < 4; ++m)                                  \
        _Pragma("unroll") for (int n = 0; n < 2; ++n) {                            \
            const f32x4 sv   = ACC[m][n];                                          \
            const f32x4 base = sv - MARGIN;                                        \
            const f32x4 alt  = 1.0f - sv;                                          \
            const int jj = c0 + n * 16 + lm;                                       \
            _Pragma("unroll") for (int r = 0; r < 4; ++r) {                        \
                const int ii = r0w + m * 16 + rb + r;                              \
                const float bv = fmaxf(base[r], 0.0f);                             \
                const float tv = (liv[m][r] == LJ[n]) ? alt[r] : bv;               \
                vsum[r] += (ii < jj) ? tv : 0.0f;                                  \
            }                                                                      \
        }

// One pipeline step for tile SX: sync; stage SX+2; prefetch labels + issue
// ds_read+MFMA for SX+1 into ACC_N/LJ_N; then epilogue of SX from ACC_C/LJ_C
// (overlaps the in-flight MFMAs and stage).  BSEL = (SX+1)&1 as a literal.
#define ITER(SX, BSEL, ACC_C, ACC_N, LJ_C, LJ_N) do {                              \
    const int sx_ = (SX);                                                          \
    __syncthreads();                                                               \
    if (sx_ + 2 < nsub) stage64(en, jb128 + (sx_ + 2) * 64, &buf[sx_ & 1][0], tid);\
    if (sx_ + 1 < nsub) {                                                          \
        const int c0n = jb128 + (sx_ + 1) * 64 + wc * 32;                          \
        LJ_N[0] = labels[c0n + lm];                                                \
        LJ_N[1] = labels[c0n + 16 + lm];                                           \
        _Pragma("unroll") for (int m = 0; m < 4; ++m)                              \
            _Pragma("unroll") for (int n = 0; n < 2; ++n)                          \
                ACC_N[m][n] = (f32x4){0.0f, 0.0f, 0.0f, 0.0f};                     \
        _Pragma("unroll") for (int ks = 0; ks < 4; ++ks) {                         \
            const short8 b0 = *(const short8*)(bbase + (BSEL) * 16384 + boff[0][ks]); \
            const short8 b1 = *(const short8*)(bbase + (BSEL) * 16384 + boff[1][ks]); \
            _Pragma("unroll") for (int m = 0; m < 4; ++m) {                        \
                ACC_N[m][0] = __builtin_amdgcn_mfma_f32_16x16x32_bf16(a[m][ks], b0, ACC_N[m][0], 0, 0, 0); \
                ACC_N[m][1] = __builtin_amdgcn_mfma_f32_16x16x32_bf16(a[m][ks], b1, ACC_N[m][1], 0, 0, 0); \
            }                                                                      \
        }                                                                          \
    }                                                                              \
    {                                                                              \
        const int c0 = jb128 + sx_ * 64 + wc * 32; (void)c0;                       \
        if (hasdiag && sx_ < 2) { EPI_DIAG(ACC_C, LJ_C) } else { EPI_FAST(ACC_C, LJ_C) } \
    }                                                                              \
} while (0)

__global__ void __launch_bounds__(256, 2)
tri_loss_kernel(const short* __restrict__ en, const int* __restrict__ labels,
                float* __restrict__ partials, int nt) {
    __shared__ __align__(16) short buf[2][64 * DIM];   // 2 x 16 KB
    __shared__ float wsum[4];

    // exact (strip bi, chunk t) decode: no dead blocks
    int t  = blockIdx.x;
    int bi = 0, cnt = (nt + CHUNK - 1) / CHUNK;
    #pragma unroll 1
    while (t >= cnt) { t -= cnt; ++bi; cnt = (nt - bi + CHUNK - 1) / CHUNK; }
    const int jbase = bi + t * CHUNK;
    const int jb128 = jbase * 128;
    const int nsub  = 2 * min(CHUNK, nt - jbase);
    const bool hasdiag = (jbase == bi);

    const int tid  = threadIdx.x;
    const int lane = tid & 63;
    const int wid  = tid >> 6;          // 4 waves = 2x2 over (128 rows x 64 cols)
    const int wr   = wid >> 1, wc = wid & 1;
    const int lm   = lane & 15;
    const int hi   = lane >> 4;
    const int rb   = hi * 4;

    // ---- stage A strip halves into the two buffers ----
    stage64(en, bi * 128,      &buf[0][0], tid);
    stage64(en, bi * 128 + 64, &buf[1][0], tid);

    // row labels -> scalar regs (static indexing)
    const int r0w = bi * 128 + wr * 64;
    int liv[4][4];
    #pragma unroll
    for (int m = 0; m < 4; ++m) {
        const int4 v = *(const int4*)(labels + r0w + m * 16 + rb);
        liv[m][0] = v.x; liv[m][1] = v.y; liv[m][2] = v.z; liv[m][3] = v.w;
    }

    __syncthreads();                    // A staged

    // ---- extract A fragments (wave's 64 rows, full K=128) ----
    short8 a[4][4];
    const short* Abuf = &buf[wr][0];
    #pragma unroll
    for (int m = 0; m < 4; ++m)
        #pragma unroll
        for (int ks = 0; ks < 4; ++ks)
            a[m][ks] = read_frag(Abuf, m * 16 + lm, hi + ks * 4);

    // precomputed B-fragment byte offsets within a 16 KB buffer
    const char* bbase = (const char*)&buf[0][0];
    int boff[2][4];
    #pragma unroll
    for (int n = 0; n < 2; ++n) {
        const int row = wc * 32 + n * 16 + lm;
        #pragma unroll
        for (int ks = 0; ks < 4; ++ks)
            boff[n][ks] = row * 256 + (((hi + ks * 4) ^ (row & 7)) << 4);
    }

    __syncthreads();                    // A reads done -> bufs reusable

    // ---- stage B subtiles 0 and 1 ----
    stage64(en, jb128,      &buf[0][0], tid);
    stage64(en, jb128 + 64, &buf[1][0], tid);
    __syncthreads();                    // B0/B1 staged

    f32x4 accA[4][2], accB[4][2];
    int   ljA[2], ljB[2];
    f32x4 vsum = (f32x4){0.0f, 0.0f, 0.0f, 0.0f};

    // prologue: labels + MFMA for subtile 0 -> accA  (BSEL 0)
    {
        const int c00 = jb128 + wc * 32;
        ljA[0] = labels[c00 + lm];
        ljA[1] = labels[c00 + 16 + lm];
        #pragma unroll
        for (int m = 0; m < 4; ++m)
            #pragma unroll
            for (int n = 0; n < 2; ++n)
                accA[m][n] = (f32x4){0.0f, 0.0f, 0.0f, 0.0f};
        #pragma unroll
        for (int ks = 0; ks < 4; ++ks) {
            const short8 b0 = *(const short8*)(bbase + boff[0][ks]);
            const short8 b1 = *(const short8*)(bbase + boff[1][ks]);
            #pragma unroll
            for (int m = 0; m < 4; ++m) {
                accA[m][0] = __builtin_amdgcn_mfma_f32_16x16x32_bf16(a[m][ks], b0, accA[m][0], 0, 0, 0);
                accA[m][1] = __builtin_amdgcn_mfma_f32_16x16x32_bf16(a[m][ks], b1, accA[m][1], 0, 0, 0);
            }
        }
    }

    #pragma unroll 1
    for (int s = 0; s < nsub; s += 2) {
        ITER(s,     1, accA, accB, ljA, ljB);
        ITER(s + 1, 0, accB, accA, ljB, ljA);
    }

    float lsum = vsum[0] + vsum[1] + vsum[2] + vsum[3];
    #pragma unroll
    for (int off = 32; off; off >>= 1) lsum += __shfl_down(lsum, off, 64);
    if (lane == 0) wsum[wid] = lsum;
    __syncthreads();
    if (tid == 0) partials[blockIdx.x] = wsum[0] + wsum[1] + wsum[2] + wsum[3];
}

// ---------------- K3: final deterministic reduce ----------------
__global__ void __launch_bounds__(256) final_reduce_kernel(const float* __restrict__ partials,
                                                           float* __restrict__ out,
                                                           int n, float inv_denom) {
    float s = 0.0f;
    for (int i = threadIdx.x; i < n; i += 256) s += partials[i];
    #pragma unroll
    for (int off = 32; off; off >>= 1) s += __shfl_xor(s, off, 64);
    __shared__ float wsum[4];
    if ((threadIdx.x & 63) == 0) wsum[threadIdx.x >> 6] = s;
    __syncthreads();
    if (threadIdx.x == 0) out[0] = (wsum[0] + wsum[1] + wsum[2] + wsum[3]) * inv_denom;
}

extern "C" void kernel_launch(void* const* d_in, const int* in_sizes, int n_in,
                              void* d_out, int out_size, void* d_ws, size_t ws_size,
                              hipStream_t stream) {
    const float* emb    = (const float*)d_in[0];
    const int*   labels = (const int*)d_in[1];
    float*       out    = (float*)d_out;

    const int n  = in_sizes[1];      // 8192
    const int nt = n / 128;          // 64 strips

    int Tc = 0;                      // 544 blocks at CHUNK=4
    for (int i = 0; i < nt; ++i) Tc += (nt - i + CHUNK - 1) / CHUNK;

    unsigned int* en_packed = (unsigned int*)d_ws;                 // 2 MB
    short*        en        = (short*)d_ws;
    float*        partials  = (float*)((char*)d_ws + (size_t)n * DIM * 2);

    norm_bf16_kernel<<<n / 4, 256, 0, stream>>>(emb, en_packed);

    tri_loss_kernel<<<Tc, 256, 0, stream>>>(en, labels, partials, nt);

    const float inv_denom = (float)(1.0 / ((double)n * (double)(n - 1)));
    final_reduce_kernel<<<1, 256, 0, stream>>>(partials, out, Tc, inv_denom);
}